// Round 10
// baseline (304.404 us; speedup 1.0000x reference)
//
#include <hip/hip_runtime.h>
#include <float.h>
#include <limits.h>

#define N_Q 8192
#define M_PTS 50000
#define DIM 128
#define KNN 10
#define NCLS 10
#define NCHUNK 16          // 16 chunks x 196 tiles (3136 tiles, 11 padded)
#define TPC 196            // tiles per chunk (uniform, compile-time)
#define CPC 8              // candidates kept per (query, chunk)
#define NCAND (NCHUNK*CPC) // 128 candidates per query
#define NSEL 24            // exact-rescored candidates per query (fp8 noise margin)
#define TPL 4              // per-lane-class top depth
#define QPB 128            // queries per block (4 waves x 32)
#define YTHREADS 200000    // 3125 real tiles x 64 slots
#define PTHREADS 232768    // + 8192 x 4 x-slices

typedef __attribute__((ext_vector_type(8))) int i32x8;
typedef __attribute__((ext_vector_type(4))) float f32x4;
typedef unsigned int u32;

// ---------------------------------------------------------------------------
// fp32 -> OCP e4m3fn, RNE, FTZ below 2^-6 (abs err <= 0.0156, negligible).
// ---------------------------------------------------------------------------
__device__ __forceinline__ u32 to_e4m3(float f) {
    u32 u = __float_as_uint(f);
    u32 s = (u >> 24) & 0x80u;
    u32 au = u & 0x7FFFFFFFu;
    if (au > 0x43E00000u) au = 0x43E00000u;           // clamp to 448
    u32 r = au + 0x0007FFFFu + ((au >> 20) & 1u);     // RNE to 3-bit mantissa
    int e = (int)(r >> 23) - 127;
    if (e < -6) return s;                             // FTZ / zero
    return s | (u32)((e + 7) << 3) | ((r >> 20) & 7u);
}

__device__ __forceinline__ u32 pack4_e4m3(float4 v, float sc) {
    return to_e4m3(sc * v.x) | (to_e4m3(sc * v.y) << 8) |
           (to_e4m3(sc * v.z) << 16) | (to_e4m3(sc * v.w) << 24);
}

// ---------------------------------------------------------------------------
// Prep: yt8 = e4m3(y) in MFMA B-fragment tile records (2 KB/tile: slot l =
// g*16+nr holds point nr, k in [32g,32g+32), 32 bytes contiguous -> coalesced
// 32B writes); y2 = ||y_j||^2 fp32 folded from the same read; xb8 = e4m3(-2x)
// row-major (128 B rows). Thread t<YTHREADS: one (tile,slot); else one
// (x-row, k-group).
// ---------------------------------------------------------------------------
__global__ __launch_bounds__(256) void prep_kernel(
    const float4* __restrict__ x4, const float4* __restrict__ y4,
    u32* __restrict__ xb8, u32* __restrict__ yt8, float* __restrict__ y2) {
    int t = blockIdx.x * 256 + threadIdx.x;
    if (t < YTHREADS) {
        int T = t >> 6, l = t & 63, nr = l & 15, g = l >> 4;
        const float4* src = y4 + ((size_t)(T * 16 + nr) * DIM + g * 32) / 4;
        u32 w[8];
        float ss = 0.f;
        #pragma unroll
        for (int i = 0; i < 8; ++i) {
            float4 v = src[i];
            ss += v.x * v.x + v.y * v.y + v.z * v.z + v.w * v.w;
            w[i] = pack4_e4m3(v, 1.0f);
        }
        uint4* dst = (uint4*)(yt8 + (size_t)T * 512 + l * 8);
        dst[0] = make_uint4(w[0], w[1], w[2], w[3]);
        dst[1] = make_uint4(w[4], w[5], w[6], w[7]);
        ss += __shfl_xor(ss, 16, 64);
        ss += __shfl_xor(ss, 32, 64);
        if (l < 16) y2[T * 16 + l] = ss;
    } else if (t < PTHREADS) {
        int tx = t - YTHREADS, row = tx >> 2, g = tx & 3;
        const float4* src = x4 + ((size_t)row * DIM + g * 32) / 4;
        u32 w[8];
        #pragma unroll
        for (int i = 0; i < 8; ++i) w[i] = pack4_e4m3(src[i], -2.0f);
        uint4* dst = (uint4*)(xb8 + (size_t)row * 32 + g * 8);
        dst[0] = make_uint4(w[0], w[1], w[2], w[3]);
        dst[1] = make_uint4(w[4], w[5], w[6], w[7]);
    }
}

// ---------------------------------------------------------------------------
// Filter: fp8 e4m3 16x16x128 scaled-MFMA (unit scales 0x7F = 2^0) -> the
// WHOLE K in one instruction. score = y2[col] - 2 x.y arrives as the raw
// MFMA output (y2 in C, -2 folded into A). Per tile: 2 MFMA + 3 VMEM; per
// score: bfi + min + 3 med3. No LDS/barriers in the loop; trip count 196
// uniform (padded tiles carry y2=3.4e38 -> never selected; 0xAA pad bytes
// are valid fp8). LDS only for the final merge.
// ---------------------------------------------------------------------------
__global__ __launch_bounds__(256, 4) void knn_filter(
    const u32* __restrict__ xb8, const u32* __restrict__ yt8,
    const float* __restrict__ y2, u32* __restrict__ ckey) {
    const int lane = threadIdx.x & 63;
    const int wid  = threadIdx.x >> 6;      // wave 0..3
    const int g    = lane >> 4;             // k-group 0..3
    const int nrow = lane & 15;             // point-in-tile (B col / C col)
    const int chunk = blockIdx.x;           // gridDim.x=16 -> XCD = chunk%8
    const int qb    = blockIdx.y;
    const int qw = qb * QPB + wid * 32;

    // A fragments: 2 query-sets, 8 dwords each (32 fp8 = k-slice 32g..32g+31)
    i32x8 a[2];
    #pragma unroll
    for (int s = 0; s < 2; ++s)
        a[s] = *(const i32x8*)(xb8 + (size_t)(qw + s * 16 + nrow) * 32 + g * 8);

    float ts[8][TPL];
    #pragma unroll
    for (int r = 0; r < 8; ++r)
        #pragma unroll
        for (int l = 0; l < TPL; ++l) ts[r][l] = FLT_MAX;

    const u32* ytp = yt8 + (size_t)chunk * TPC * 512 + lane * 8;
    const float* y2p = y2 + chunk * TPC * 16 + nrow;

    #pragma unroll 2
    for (int t = 0; t < TPC; ++t) {
        i32x8 b = *(const i32x8*)(ytp + (size_t)t * 512);
        float y2n = y2p[t * 16];
        f32x4 cq = {y2n, y2n, y2n, y2n};
        f32x4 d0 = __builtin_amdgcn_mfma_scale_f32_16x16x128_f8f6f4(
            a[0], b, cq, 0, 0, 0, 0x7F7F7F7F, 0, 0x7F7F7F7F);
        f32x4 d1 = __builtin_amdgcn_mfma_scale_f32_16x16x128_f8f6f4(
            a[1], b, cq, 0, 0, 0, 0x7F7F7F7F, 0, 0x7F7F7F7F);
        u32 rel = (u32)(t * 16) | (u32)nrow;          // < 3136, 12 bits
        #pragma unroll
        for (int i = 0; i < 4; ++i) {
            float key = __uint_as_float((__float_as_uint(d0[i]) & 0xFFFFF000u) | rel);
            float o0 = ts[i][0], o1 = ts[i][1], o2 = ts[i][2];
            ts[i][0] = fminf(o0, key);
            ts[i][1] = __builtin_amdgcn_fmed3f(key, o0, o1);
            ts[i][2] = __builtin_amdgcn_fmed3f(key, o1, o2);
            ts[i][3] = __builtin_amdgcn_fmed3f(key, o2, ts[i][3]);
        }
        #pragma unroll
        for (int i = 0; i < 4; ++i) {
            float key = __uint_as_float((__float_as_uint(d1[i]) & 0xFFFFF000u) | rel);
            float o0 = ts[4 + i][0], o1 = ts[4 + i][1], o2 = ts[4 + i][2];
            ts[4 + i][0] = fminf(o0, key);
            ts[4 + i][1] = __builtin_amdgcn_fmed3f(key, o0, o1);
            ts[4 + i][2] = __builtin_amdgcn_fmed3f(key, o1, o2);
            ts[4 + i][3] = __builtin_amdgcn_fmed3f(key, o2, ts[4 + i][3]);
        }
    }

    // ---- merge 16 lane-classes -> per-query sorted top-8 ----
    __shared__ u32 smem[QPB * 65];          // 33280 B
    #pragma unroll
    for (int s = 0; s < 2; ++s)
        #pragma unroll
        for (int r = 0; r < 4; ++r) {
            int ql = wid * 32 + s * 16 + g * 4 + r;
            #pragma unroll
            for (int l = 0; l < TPL; ++l)
                smem[ql * 65 + nrow * TPL + l] = __float_as_uint(ts[s * 4 + r][l]);
        }
    __syncthreads();
    if (threadIdx.x < QPB) {
        int ql = threadIdx.x;
        float bs[CPC];
        #pragma unroll
        for (int i = 0; i < CPC; ++i) bs[i] = FLT_MAX;
        for (int e = 0; e < 16 * TPL; ++e) {      // stride-65: conflict-free
            float f = __uint_as_float(smem[ql * 65 + e]);
            #pragma unroll
            for (int q2 = 0; q2 < CPC; ++q2) {
                float mn = fminf(bs[q2], f);
                f = fmaxf(bs[q2], f);
                bs[q2] = mn;
            }
        }
        u32* dst = ckey + ((size_t)(qb * QPB + ql) * NCHUNK + chunk) * CPC;
        #pragma unroll
        for (int i = 0; i < CPC; ++i) dst[i] = __float_as_uint(bs[i]);
    }
}

// ---------------------------------------------------------------------------
// Finalize: 8 queries/block (2/wave). Select (approx-top-24 of 128, sorted-
// chunk early-out) on lanes lane%32==0; exact fp64 rescore one candidate per
// lane (cand = lane&31 < 24); top-10 with (score,idx) tie-break = jax top_k;
// majority vote, ties -> LARGEST class.
// ---------------------------------------------------------------------------
__global__ __launch_bounds__(256) void knn_finalize(
    const u32* __restrict__ ckey, const float* __restrict__ x,
    const float* __restrict__ y, const int* __restrict__ labels,
    int* __restrict__ out) {
    const int lane = threadIdx.x & 63;
    const int wid  = threadIdx.x >> 6;
    const int qbase = blockIdx.x * 8;

    __shared__ u32 skey[8][NCAND];
    __shared__ int sidx[8][NSEL];
    __shared__ double sex[8][NSEL];

    for (int i = threadIdx.x; i < 8 * NCAND; i += 256)
        skey[i >> 7][i & 127] = ckey[(size_t)(qbase + (i >> 7)) * NCAND + (i & 127)];
    __syncthreads();

    if ((lane & 31) == 0) {                 // 2 parallel selects per wave
        int ql = wid * 2 + (lane >> 5);
        float bs[NSEL]; int bi[NSEL];
        #pragma unroll
        for (int i = 0; i < NSEL; ++i) { bs[i] = FLT_MAX; bi[i] = 0; }
        for (int c = 0; c < NCHUNK; ++c) {
            int base = c * CPC;
            for (int j = 0; j < CPC; ++j) {
                u32 u = skey[ql][base + j];
                float f = __uint_as_float(u);
                if (f >= bs[NSEL - 1]) break;   // chunk sorted: rest can't qualify
                int id = c * (TPC * 16) + (int)(u & 0xFFFu);
                #pragma unroll
                for (int pp = 0; pp < NSEL; ++pp) {
                    bool lt = f < bs[pp];
                    float nf = lt ? bs[pp] : f;  int nid = lt ? bi[pp] : id;
                    bs[pp] = lt ? f : bs[pp];    bi[pp] = lt ? id : bi[pp];
                    f = nf; id = nid;
                }
            }
        }
        #pragma unroll
        for (int i = 0; i < NSEL; ++i) sidx[ql][i] = bi[i];
    }
    __syncthreads();

    // exact fp64 rescore: lane -> (qloc = lane>>5, cand = lane&31)
    const int qloc = lane >> 5;
    const int cand = lane & 31;
    const int ql = wid * 2 + qloc;
    if (cand < NSEL) {
        const int idx = sidx[ql][cand];
        const float4* xr = (const float4*)(x + (size_t)(qbase + ql) * DIM);
        const float4* yr = (const float4*)(y + (size_t)idx * DIM);
        double dy2 = 0.0, dxy = 0.0;
        #pragma unroll 8
        for (int i = 0; i < 32; ++i) {
            float4 yv = yr[i];
            float4 xv = xr[i];
            dy2 = fma((double)yv.x, (double)yv.x, dy2);
            dy2 = fma((double)yv.y, (double)yv.y, dy2);
            dy2 = fma((double)yv.z, (double)yv.z, dy2);
            dy2 = fma((double)yv.w, (double)yv.w, dy2);
            dxy = fma((double)xv.x, (double)yv.x, dxy);
            dxy = fma((double)xv.y, (double)yv.y, dxy);
            dxy = fma((double)xv.z, (double)yv.z, dxy);
            dxy = fma((double)xv.w, (double)yv.w, dxy);
        }
        sex[ql][cand] = dy2 - 2.0 * dxy;
    }
    __syncthreads();

    if ((lane & 31) == 0) {                 // 2 parallel votes per wave
        int ql2 = wid * 2 + (lane >> 5);
        double tsv[KNN]; int ti[KNN];
        #pragma unroll
        for (int i = 0; i < KNN; ++i) { tsv[i] = 1e300; ti[i] = INT_MAX; }
        #pragma unroll
        for (int c = 0; c < NSEL; ++c) {
            double s = sex[ql2][c];
            int id = sidx[ql2][c];
            #pragma unroll
            for (int pp = 0; pp < KNN; ++pp) {
                bool lt = (s < tsv[pp]) || (s == tsv[pp] && id < ti[pp]);
                double ns = lt ? tsv[pp] : s;  int nid = lt ? ti[pp] : id;
                tsv[pp] = lt ? s : tsv[pp];    ti[pp] = lt ? id : ti[pp];
                s = ns; id = nid;
            }
        }
        int lab[KNN];
        #pragma unroll
        for (int i = 0; i < KNN; ++i) lab[i] = labels[ti[i]];
        int bestc = 0, bestn = -1;
        #pragma unroll
        for (int c = 0; c < NCLS; ++c) {
            int n = 0;
            #pragma unroll
            for (int i = 0; i < KNN; ++i) n += (lab[i] == c) ? 1 : 0;
            if (n >= bestn) { bestn = n; bestc = c; }   // >= : ties -> larger label
        }
        out[qbase + ql2] = bestc;
    }
}

// ---------------------------------------------------------------------------
extern "C" void kernel_launch(void* const* d_in, const int* in_sizes, int n_in,
                              void* d_out, int out_size, void* d_ws, size_t ws_size,
                              hipStream_t stream) {
    const float* x      = (const float*)d_in[0];
    const float* y      = (const float*)d_in[1];
    const int*   labels = (const int*)d_in[2];
    // d_in[3] is k == 10, baked in.

    char* ws = (char*)d_ws;
    size_t off = 0;
    u32* xb8 = (u32*)(ws + off);    off += (size_t)N_Q * DIM;            //  1.05 MB
    u32* yt8 = (u32*)(ws + off);    off += (size_t)NCHUNK * TPC * 2048;  //  6.42 MB
    float* y2 = (float*)(ws + off); off += (size_t)NCHUNK * TPC * 16 * 4;//  0.20 MB
    u32* ckey = (u32*)(ws + off);   off += (size_t)N_Q * NCAND * 4;      //  4.19 MB
    int* out = (int*)d_out;

    // pad y2 (tiles 3125..3135) with huge finite floats (0x7F7F7F7F ~ 3.4e38)
    hipMemsetAsync(y2, 0x7F, (size_t)NCHUNK * TPC * 16 * 4, stream);
    prep_kernel<<<(PTHREADS + 255) / 256, 256, 0, stream>>>(
        (const float4*)x, (const float4*)y, xb8, yt8, y2);
    knn_filter<<<dim3(NCHUNK, N_Q / QPB), 256, 0, stream>>>(xb8, yt8, y2, ckey);
    knn_finalize<<<N_Q / 8, 256, 0, stream>>>(ckey, x, y, labels, out);
}

// Round 12
// 259.249 us; speedup vs baseline: 1.1742x; 1.1742x over previous
//
#include <hip/hip_runtime.h>
#include <float.h>
#include <limits.h>

#define N_Q 8192
#define M_PTS 50000
#define DIM 128
#define KNN 10
#define NCLS 10
#define NCHUNK 16          // 16 chunks x 196 tiles (3136 tiles, 11 padded)
#define TPC 196            // tiles per chunk (uniform, compile-time)
#define CPC 8              // candidates kept per (query, chunk)
#define NCAND (NCHUNK*CPC) // 128 candidates per query
#define NSEL 24            // exact-rescored candidates per query
#define TPL 4              // per-lane-class top depth
#define QPB 64             // queries per block (4 waves x 16)
#define SBIAS 256.0f       // score bias: keys guaranteed positive -> u32 order == float order
#define YTHREADS 200000    // 3125 real tiles x 64 slots
#define PTHREADS 232768    // + 8192 x 4 x-slices
#define ATHREADS 232944    // + 176 y2 pad entries

typedef __attribute__((ext_vector_type(8))) int i32x8;
typedef __attribute__((ext_vector_type(4))) float f32x4;
typedef unsigned int u32;

// ---------------------------------------------------------------------------
// fp32 -> OCP e4m3fn, RNE, FTZ below 2^-6.
// ---------------------------------------------------------------------------
__device__ __forceinline__ u32 to_e4m3(float f) {
    u32 u = __float_as_uint(f);
    u32 s = (u >> 24) & 0x80u;
    u32 au = u & 0x7FFFFFFFu;
    if (au > 0x43E00000u) au = 0x43E00000u;           // clamp to 448
    u32 r = au + 0x0007FFFFu + ((au >> 20) & 1u);     // RNE to 3-bit mantissa
    int e = (int)(r >> 23) - 127;
    if (e < -6) return s;                             // FTZ / zero
    return s | (u32)((e + 7) << 3) | ((r >> 20) & 7u);
}

__device__ __forceinline__ u32 pack4_e4m3(float4 v, float sc) {
    return to_e4m3(sc * v.x) | (to_e4m3(sc * v.y) << 8) |
           (to_e4m3(sc * v.z) << 16) | (to_e4m3(sc * v.w) << 24);
}

// ---------------------------------------------------------------------------
// Prep: yt8 = e4m3(y) in B-fragment tile records (2 KB/tile, slot l = g*16+nr
// holds point nr, k in [32g,32g+32)); y2 = ||y_j||^2 fp32 (pad entries
// 50000..50175 = FLT_MAX via tail threads); xb8 = e4m3(-2x) row-major.
// ---------------------------------------------------------------------------
__global__ __launch_bounds__(256) void prep_kernel(
    const float4* __restrict__ x4, const float4* __restrict__ y4,
    u32* __restrict__ xb8, u32* __restrict__ yt8, float* __restrict__ y2) {
    int t = blockIdx.x * 256 + threadIdx.x;
    if (t < YTHREADS) {
        int T = t >> 6, l = t & 63, nr = l & 15, g = l >> 4;
        const float4* src = y4 + ((size_t)(T * 16 + nr) * DIM + g * 32) / 4;
        u32 w[8];
        float ss = 0.f;
        #pragma unroll
        for (int i = 0; i < 8; ++i) {
            float4 v = src[i];
            ss += v.x * v.x + v.y * v.y + v.z * v.z + v.w * v.w;
            w[i] = pack4_e4m3(v, 1.0f);
        }
        uint4* dst = (uint4*)(yt8 + (size_t)T * 512 + l * 8);
        dst[0] = make_uint4(w[0], w[1], w[2], w[3]);
        dst[1] = make_uint4(w[4], w[5], w[6], w[7]);
        ss += __shfl_xor(ss, 16, 64);
        ss += __shfl_xor(ss, 32, 64);
        if (l < 16) y2[T * 16 + l] = ss;
    } else if (t < PTHREADS) {
        int tx = t - YTHREADS, row = tx >> 2, g = tx & 3;
        const float4* src = x4 + ((size_t)row * DIM + g * 32) / 4;
        u32 w[8];
        #pragma unroll
        for (int i = 0; i < 8; ++i) w[i] = pack4_e4m3(src[i], -2.0f);
        uint4* dst = (uint4*)(xb8 + (size_t)row * 32 + g * 8);
        dst[0] = make_uint4(w[0], w[1], w[2], w[3]);
        dst[1] = make_uint4(w[4], w[5], w[6], w[7]);
    } else if (t < ATHREADS) {
        y2[M_PTS + (t - PTHREADS)] = FLT_MAX;   // pad tiles: never selected
    }
}

// ---------------------------------------------------------------------------
// Filter: fp8 e4m3 16x16x128 scaled-MFMA (unit scales), one query-set per
// wave (16 queries) so live state (~50 regs) fits arch VGPRs at 8 waves/SIMD.
// score+SBIAS = (y2[col]+SBIAS) - 2 x.y arrives as the raw MFMA output (bias
// +y2 in C, -2 folded into A); bias makes every key positive so the finalize
// rank-select can compare keys as u32 (round-11 bug: negative scores sorted
// last in u32 order -> true nearest neighbors dropped). Per tile: 1 MFMA +
// 3 VMEM + ~26 VALU. No LDS/barriers in the loop.
// ---------------------------------------------------------------------------
__global__ __launch_bounds__(256, 8) void knn_filter(
    const u32* __restrict__ xb8, const u32* __restrict__ yt8,
    const float* __restrict__ y2, u32* __restrict__ ckey) {
    const int lane = threadIdx.x & 63;
    const int wid  = threadIdx.x >> 6;      // wave 0..3
    const int g    = lane >> 4;             // k-group 0..3
    const int nrow = lane & 15;             // point-in-tile (B col / C col)
    const int chunk = blockIdx.x;           // gridDim.x=16 -> XCD = chunk%8
    const int qb    = blockIdx.y;
    const int qw = qb * QPB + wid * 16;

    // A fragment: 8 dwords = 32 fp8 of row (qw+nrow), k-slice [32g, 32g+32)
    i32x8 a = *(const i32x8*)(xb8 + (size_t)(qw + nrow) * 32 + g * 8);

    float ts[4][TPL];
    #pragma unroll
    for (int r = 0; r < 4; ++r)
        #pragma unroll
        for (int l = 0; l < TPL; ++l) ts[r][l] = FLT_MAX;

    const u32* ytp = yt8 + (size_t)chunk * TPC * 512 + lane * 8;
    const float* y2p = y2 + chunk * TPC * 16 + nrow;

    for (int t = 0; t < TPC; ++t) {
        i32x8 b = *(const i32x8*)(ytp + (size_t)t * 512);
        float y2n = y2p[t * 16] + SBIAS;
        f32x4 cq = {y2n, y2n, y2n, y2n};
        f32x4 d = __builtin_amdgcn_mfma_scale_f32_16x16x128_f8f6f4(
            a, b, cq, 0, 0, 0, 0x7F7F7F7F, 0, 0x7F7F7F7F);
        u32 rel = (u32)(t * 16) | (u32)nrow;          // < 3136, 12 bits
        #pragma unroll
        for (int i = 0; i < 4; ++i) {
            float key = __uint_as_float((__float_as_uint(d[i]) & 0xFFFFF000u) | rel);
            float o0 = ts[i][0], o1 = ts[i][1], o2 = ts[i][2];
            ts[i][0] = fminf(o0, key);
            ts[i][1] = __builtin_amdgcn_fmed3f(key, o0, o1);
            ts[i][2] = __builtin_amdgcn_fmed3f(key, o1, o2);
            ts[i][3] = __builtin_amdgcn_fmed3f(key, o2, ts[i][3]);
        }
    }

    // ---- merge 16 lane-classes -> per-query sorted top-8 ----
    __shared__ u32 smem[QPB * 65];          // 16640 B
    #pragma unroll
    for (int r = 0; r < 4; ++r) {
        int ql = wid * 16 + g * 4 + r;      // C row = g*4 + reg
        #pragma unroll
        for (int l = 0; l < TPL; ++l)
            smem[ql * 65 + nrow * TPL + l] = __float_as_uint(ts[r][l]);
    }
    __syncthreads();
    if (threadIdx.x < QPB) {
        int ql = threadIdx.x;
        float bs[CPC];
        #pragma unroll
        for (int i = 0; i < CPC; ++i) bs[i] = FLT_MAX;
        for (int e = 0; e < 16 * TPL; ++e) {      // stride-65: conflict-free
            float f = __uint_as_float(smem[ql * 65 + e]);
            #pragma unroll
            for (int q2 = 0; q2 < CPC; ++q2) {
                float mn = fminf(bs[q2], f);
                f = fmaxf(bs[q2], f);
                bs[q2] = mn;
            }
        }
        u32* dst = ckey + ((size_t)(qb * QPB + ql) * NCHUNK + chunk) * CPC;
        #pragma unroll
        for (int i = 0; i < CPC; ++i) dst[i] = __float_as_uint(bs[i]);
    }
}

// ---------------------------------------------------------------------------
// Finalize: 8 queries/block, half-wave per query. Select = parallel exact
// rank (count (key,pos)-smaller over the 128 keys; keys are biased-positive
// floats -> u32 compare is correct; position tie-break keeps ranks unique);
// rank<24 writes its slot. Exact fp64 rescore one cand/sub-lane; serial
// top-10 + vote on sub-lane 0 ((score,idx) tie = jax top_k stability; class
// ties -> LARGEST label).
// ---------------------------------------------------------------------------
__global__ __launch_bounds__(256) void knn_finalize(
    const u32* __restrict__ ckey, const float* __restrict__ x,
    const float* __restrict__ y, const int* __restrict__ labels,
    int* __restrict__ out) {
    const int lane = threadIdx.x & 63;
    const int wid  = threadIdx.x >> 6;
    const int qbase = blockIdx.x * 8;
    const int ql = wid * 2 + (lane >> 5);   // query-in-block 0..7
    const int sl = lane & 31;               // sub-lane in half-wave

    __shared__ u32 skey[8][NCAND];
    __shared__ int sidx[8][NSEL];
    __shared__ double sex[8][NSEL];

    for (int i = threadIdx.x; i < 8 * NCAND; i += 256)
        skey[i >> 7][i & 127] = ckey[(size_t)(qbase + (i >> 7)) * NCAND + (i & 127)];
    __syncthreads();

    // parallel rank select: 4 candidates per sub-lane, one kj read per j
    {
        u32 ke[4];
        int rank[4];
        #pragma unroll
        for (int r0 = 0; r0 < 4; ++r0) {
            ke[r0] = skey[ql][r0 * 32 + sl];
            rank[r0] = 0;
        }
        for (int j = 0; j < NCAND; ++j) {
            u32 kj = skey[ql][j];
            #pragma unroll
            for (int r0 = 0; r0 < 4; ++r0)
                rank[r0] += (kj < ke[r0] || (kj == ke[r0] && j < r0 * 32 + sl)) ? 1 : 0;
        }
        #pragma unroll
        for (int r0 = 0; r0 < 4; ++r0) {
            if (rank[r0] < NSEL) {
                int e = r0 * 32 + sl;
                sidx[ql][rank[r0]] = (e >> 3) * (TPC * 16) + (int)(ke[r0] & 0xFFFu);
            }
        }
    }
    __syncthreads();

    // exact fp64 rescore: sub-lanes 0..23
    if (sl < NSEL) {
        const int idx = sidx[ql][sl];
        const float4* xr = (const float4*)(x + (size_t)(qbase + ql) * DIM);
        const float4* yr = (const float4*)(y + (size_t)idx * DIM);
        double dy2 = 0.0, dxy = 0.0;
        #pragma unroll 8
        for (int i = 0; i < 32; ++i) {
            float4 yv = yr[i];
            float4 xv = xr[i];
            dy2 = fma((double)yv.x, (double)yv.x, dy2);
            dy2 = fma((double)yv.y, (double)yv.y, dy2);
            dy2 = fma((double)yv.z, (double)yv.z, dy2);
            dy2 = fma((double)yv.w, (double)yv.w, dy2);
            dxy = fma((double)xv.x, (double)yv.x, dxy);
            dxy = fma((double)xv.y, (double)yv.y, dxy);
            dxy = fma((double)xv.z, (double)yv.z, dxy);
            dxy = fma((double)xv.w, (double)yv.w, dxy);
        }
        sex[ql][sl] = dy2 - 2.0 * dxy;
    }
    __syncthreads();

    if (sl == 0) {
        double tsv[KNN]; int ti[KNN];
        #pragma unroll
        for (int i = 0; i < KNN; ++i) { tsv[i] = 1e300; ti[i] = INT_MAX; }
        #pragma unroll
        for (int c = 0; c < NSEL; ++c) {
            double s = sex[ql][c];
            int id = sidx[ql][c];
            #pragma unroll
            for (int pp = 0; pp < KNN; ++pp) {
                bool lt = (s < tsv[pp]) || (s == tsv[pp] && id < ti[pp]);
                double ns = lt ? tsv[pp] : s;  int nid = lt ? ti[pp] : id;
                tsv[pp] = lt ? s : tsv[pp];    ti[pp] = lt ? id : ti[pp];
                s = ns; id = nid;
            }
        }
        int lab[KNN];
        #pragma unroll
        for (int i = 0; i < KNN; ++i) lab[i] = labels[ti[i]];
        int bestc = 0, bestn = -1;
        #pragma unroll
        for (int c = 0; c < NCLS; ++c) {
            int n = 0;
            #pragma unroll
            for (int i = 0; i < KNN; ++i) n += (lab[i] == c) ? 1 : 0;
            if (n >= bestn) { bestn = n; bestc = c; }   // >= : ties -> larger label
        }
        out[qbase + ql] = bestc;
    }
}

// ---------------------------------------------------------------------------
extern "C" void kernel_launch(void* const* d_in, const int* in_sizes, int n_in,
                              void* d_out, int out_size, void* d_ws, size_t ws_size,
                              hipStream_t stream) {
    const float* x      = (const float*)d_in[0];
    const float* y      = (const float*)d_in[1];
    const int*   labels = (const int*)d_in[2];
    // d_in[3] is k == 10, baked in.

    char* ws = (char*)d_ws;
    size_t off = 0;
    u32* xb8 = (u32*)(ws + off);    off += (size_t)N_Q * DIM;            //  1.05 MB
    u32* yt8 = (u32*)(ws + off);    off += (size_t)NCHUNK * TPC * 2048;  //  6.42 MB
    float* y2 = (float*)(ws + off); off += (size_t)NCHUNK * TPC * 16 * 4;//  0.20 MB
    u32* ckey = (u32*)(ws + off);   off += (size_t)N_Q * NCAND * 4;      //  4.19 MB
    int* out = (int*)d_out;

    prep_kernel<<<(ATHREADS + 255) / 256, 256, 0, stream>>>(
        (const float4*)x, (const float4*)y, xb8, yt8, y2);
    knn_filter<<<dim3(NCHUNK, N_Q / QPB), 256, 0, stream>>>(xb8, yt8, y2, ckey);
    knn_finalize<<<N_Q / 8, 256, 0, stream>>>(ckey, x, y, labels, out);
}